// Round 15
// baseline (3443.586 us; speedup 1.0000x reference)
//
#include <hip/hip_runtime.h>
#include <math.h>

// Problem constants (from reference)
#define B_ 32
#define N_ 16384
#define K_ 21
#define C_ 64
#define M_ (N_ - K_ + 1)   // 16364
#define T_ 30
// L = 10.0, LAM = 0.1  ->  1/L = 0.1, LAM/L = 0.01

#define TILE 236    // x outputs per block
#define NBLK 70     // blocks per batch in m  (70*236 >= M_)
#define UPW  256    // u-partial slots per block (res width)
#define NT   512    // 8 waves; wave wv handles 8 channels (2 chunks x 4)

// ---------------- fused step (u-recursion, shuffle-based convT) -----------
// u_t = convT(x_t) kept as per-block partials up[B][NBLK][UPW] (<=2 blocks
// overlap per position -> exact deterministic sum at read time, no atomics).
// Per block (b, x): res tile from y/u; conv(res)+shrink with the residual
// window hoisted in registers; the convT window of the NEW x tile is built
// from each lane's own 4 outputs + 5x4 __shfl from lanes l-5..l-1.
// Left-pad zeros come FREE from shuffle wrap: src<0 wraps to lanes 59..63
// (ds_bpermute mod-64 addressing), whose o values are forced to 0 by the
// act predicate (act => l<59). No cndmask needed.
// 8 waves/block (512 thr): halves per-wave serial depth and cuts the
// dispatch tail (2240 blocks / ~768-block capacity = 2.9 periods vs 1.46).
// NOTE: NO __launch_bounds__ min-waves hint — round 13 showed it inflates
// FETCH/WRITE ~2-3x (L3 locality destroyed) at same VGPR.
// KEY INVARIANT: x is read/written ONLY at own positions -> x_{t+1} may
// overwrite x_{t-1} in-place (2-buffer rotation, L3-resident working set).
__global__ __launch_bounds__(NT) void fused_step4_kernel(
    const float* __restrict__ Xc, const float* __restrict__ Xo,
    float* __restrict__ Xw,
    const float* __restrict__ Ut, const float* __restrict__ Uo,
    float* __restrict__ Uw,
    const float* __restrict__ y, const float* __restrict__ Hg,
    const float bp, const float bm, const int first)
{
  __shared__ float rs[280];        // residual row (+24 zero tail)
  __shared__ float rp[8][256];     // per-wave convT partials

  const int tid = threadIdx.x;
  const int wv  = tid >> 6;        // 0..7
  const int l   = tid & 63;
  const int b   = blockIdx.y;
  const int x   = blockIdx.x;
  const int m0  = x * TILE;
  const bool has_o = (bm != 0.f);

  if (tid < 24) rs[256 + tid] = 0.f;

  // ---- residual: res = y - bp*u_t - bm*u_{t-1} (per-block u partials) ----
  if (tid < 256) {
    const int n = m0 + tid;
    float r = 0.f;
    if (n < N_) {
      r = y[(size_t)b * N_ + n];
      if (!first) {
        const float* Ub = Ut + (size_t)b * NBLK * UPW;
        float ut;
        if (tid >= 236) {
          ut = Ub[(x + 1) * UPW + tid - 236] + Ub[x * UPW + tid];
        } else {
          ut = Ub[x * UPW + tid];
          if (tid < 20 && x > 0) ut += Ub[(x - 1) * UPW + 236 + tid];
        }
        r -= bp * ut;
        if (has_o) {
          const float* Vb = Uo + (size_t)b * NBLK * UPW;
          float uo;
          if (tid >= 236) {
            uo = Vb[(x + 1) * UPW + tid - 236] + Vb[x * UPW + tid];
          } else {
            uo = Vb[x * UPW + tid];
            if (tid < 20 && x > 0) uo += Vb[(x - 1) * UPW + 236 + tid];
          }
          r -= bm * uo;
        }
      }
    }
    rs[tid] = r;
  }
  __syncthreads();

  // hoisted loop-invariant residual window (VGPR-resident all kernel)
  float wr[24];
  #pragma unroll
  for (int kk = 0; kk < 6; ++kk) {
    const float4 v = *(const float4*)&rs[(l << 2) + (kk << 2)];
    wr[4*kk+0] = v.x; wr[4*kk+1] = v.y;
    wr[4*kk+2] = v.z; wr[4*kk+3] = v.w;
  }

  const int  mown = m0 + (l << 2);
  const int  coff = (mown <= M_ - 4) ? mown : (M_ - 4);  // branchless loads
  const bool act  = (l < 59) && ((l << 2) < M_ - m0);
  const size_t bC = (size_t)b * C_;

  float p0 = 0.f, p1 = 0.f, p2 = 0.f, p3 = 0.f;

  for (int k = 0; k < 2; ++k) {    // wave wv: channels (k*32 + wv*4 + j)
    #pragma unroll
    for (int j = 0; j < 4; ++j) {
      const int cg = __builtin_amdgcn_readfirstlane((k << 5) + (wv << 2) + j);
      const float* hc = Hg + cg * K_;     // uniform -> s_loads

      // gradient conv from the register-resident residual window
      float g0 = 0.f, g1 = 0.f, g2 = 0.f, g3 = 0.f;
      #pragma unroll
      for (int u = 0; u < 21; ++u) {
        const float hv = hc[u];
        g0 = fmaf(wr[u],     hv, g0);
        g1 = fmaf(wr[u + 1], hv, g1);
        g2 = fmaf(wr[u + 2], hv, g2);
        g3 = fmaf(wr[u + 3], hv, g3);
      }

      // x_tmp at own positions
      float xt0 = 0.f, xt1 = 0.f, xt2 = 0.f, xt3 = 0.f;
      if (!first) {
        const float4 a = *(const float4*)(Xc + (bC + cg) * M_ + coff);
        float ox = 0.f, oy = 0.f, oz = 0.f, ow = 0.f;
        if (has_o) {
          const float4 o = *(const float4*)(Xo + (bC + cg) * M_ + coff);
          ox = o.x; oy = o.y; oz = o.z; ow = o.w;
        }
        xt0 = fmaf(bm, ox, bp * a.x);
        xt1 = fmaf(bm, oy, bp * a.y);
        xt2 = fmaf(bm, oz, bp * a.z);
        xt3 = fmaf(bm, ow, bp * a.w);
      }

      // shrink
      float o0 = fmaxf(fmaf(g0, 0.1f, xt0) - 0.01f, 0.f);
      float o1 = fmaxf(fmaf(g1, 0.1f, xt1) - 0.01f, 0.f);
      float o2 = fmaxf(fmaf(g2, 0.1f, xt2) - 0.01f, 0.f);
      float o3 = fmaxf(fmaf(g3, 0.1f, xt3) - 0.01f, 0.f);
      if (!act) { o0 = 0.f; o1 = 0.f; o2 = 0.f; o3 = 0.f; }
      if (act)
        *(float4*)(Xw + (bC + cg) * M_ + mown) = make_float4(o0, o1, o2, o3);

      // convT window: w[4d+i] = lane(l-5+d)'s o_i. src<0 wraps to lanes
      // 59..63 whose o are zero (act) -> free left-pad, no select needed.
      float w[24];
      w[20] = o0; w[21] = o1; w[22] = o2; w[23] = o3;
      #pragma unroll
      for (int d = 0; d < 5; ++d) {
        const int src = l - 5 + d;
        w[4*d+0] = __shfl(o0, src);
        w[4*d+1] = __shfl(o1, src);
        w[4*d+2] = __shfl(o2, src);
        w[4*d+3] = __shfl(o3, src);
      }

      // convT partials at positions m0+4l..+3
      #pragma unroll
      for (int u = 0; u < 21; ++u) {
        const float hv = hc[20 - u];
        p0 = fmaf(w[u],     hv, p0);
        p1 = fmaf(w[u + 1], hv, p1);
        p2 = fmaf(w[u + 2], hv, p2);
        p3 = fmaf(w[u + 3], hv, p3);
      }
    }
  }

  rp[wv][(l<<2)+0] = p0; rp[wv][(l<<2)+1] = p1;
  rp[wv][(l<<2)+2] = p2; rp[wv][(l<<2)+3] = p3;
  __syncthreads();

  if (tid < 256) {
    Uw[((size_t)b * NBLK + x) * UPW + tid] =
        rp[0][tid] + rp[1][tid] + rp[2][tid] + rp[3][tid] +
        rp[4][tid] + rp[5][tid] + rp[6][tid] + rp[7][tid];
  }
}

// y_hat[n] = u_30(n) from per-block partials (<=2 contributions)
__global__ __launch_bounds__(256) void yhat_combine_kernel(
    const float* __restrict__ Uw, float* __restrict__ outy)
{
  const int tid = threadIdx.x;
  const int n = blockIdx.x * 256 + tid;
  const int b = blockIdx.y;
  const int x = n / 236;
  const int i = n - x * 236;
  const float* Ub = Uw + (size_t)b * NBLK * UPW;
  float v = Ub[x * UPW + i];
  if (i < 20 && x > 0) v += Ub[(x - 1) * UPW + 236 + i];
  outy[(size_t)b * N_ + n] = v;
}

// ================= round-5 proven fallback path =================
#define XWID 276
#define Q4PC 69
#define NQ4  (16 * Q4PC)
#define NTF  256

__global__ __launch_bounds__(NTF, 4) void fused_step_r5_kernel(
    const float* __restrict__ Xc, const float* __restrict__ Xo,
    float* __restrict__ Xw, const float* __restrict__ y,
    const float* __restrict__ Hg, const float bp, const float bm,
    const int first)
{
  __shared__ float xs[16][XWID];
  __shared__ float rp[4][256];
  __shared__ float rs[256];

  const int tid = threadIdx.x;
  const int wv  = tid >> 6;
  const int l   = tid & 63;
  const int b   = blockIdx.y;
  const int m0  = blockIdx.x * TILE;
  const int g0  = m0 - 20;
  const bool has_o = (bm != 0.f);

  if (!first) {
    float p0 = 0.f, p1 = 0.f, p2 = 0.f, p3 = 0.f;
    for (int k = 0; k < 4; ++k) {
      const int ch0 = k << 4;
      const float* pcb = Xc + ((size_t)b * C_ + ch0) * M_;
      const float* pob = Xo + ((size_t)b * C_ + ch0) * M_;
      __syncthreads();
      for (int f = tid; f < NQ4; f += NTF) {
        const int c  = f / Q4PC;
        const int i4 = f - c * Q4PC;
        const int g  = g0 + (i4 << 2);
        const float* pa = pcb + (size_t)c * M_ + g;
        const float* pb = pob + (size_t)c * M_ + g;
        float ax, ay, az, aw, ox, oy, oz, ow;
        if (g >= 0 && g + 3 < M_) {
          const float4 a = *(const float4*)pa;
          ax = a.x; ay = a.y; az = a.z; aw = a.w;
          if (has_o) {
            const float4 o = *(const float4*)pb;
            ox = o.x; oy = o.y; oz = o.z; ow = o.w;
          } else { ox = oy = oz = ow = 0.f; }
        } else {
          ax = ay = az = aw = ox = oy = oz = ow = 0.f;
          if ((unsigned)(g+0) < (unsigned)M_) { ax = pa[0]; if (has_o) ox = pb[0]; }
          if ((unsigned)(g+1) < (unsigned)M_) { ay = pa[1]; if (has_o) oy = pb[1]; }
          if ((unsigned)(g+2) < (unsigned)M_) { az = pa[2]; if (has_o) oz = pb[2]; }
          if ((unsigned)(g+3) < (unsigned)M_) { aw = pa[3]; if (has_o) ow = pb[3]; }
        }
        float4 w4;
        w4.x = fmaf(bm, ox, bp * ax);
        w4.y = fmaf(bm, oy, bp * ay);
        w4.z = fmaf(bm, oz, bp * az);
        w4.w = fmaf(bm, ow, bp * aw);
        *(float4*)&xs[c][i4 << 2] = w4;
      }
      __syncthreads();
      #pragma unroll
      for (int j = 0; j < 4; ++j) {
        const int cloc = (wv << 2) + j;
        const int cg = __builtin_amdgcn_readfirstlane(ch0 + cloc);
        const float* hc = Hg + cg * K_;
        float w[24];
        #pragma unroll
        for (int kk = 0; kk < 6; ++kk) {
          const float4 v = *(const float4*)&xs[cloc][(l << 2) + (kk << 2)];
          w[4*kk+0] = v.x; w[4*kk+1] = v.y;
          w[4*kk+2] = v.z; w[4*kk+3] = v.w;
        }
        #pragma unroll
        for (int u = 0; u < 21; ++u) {
          const float hv = hc[20 - u];
          p0 = fmaf(w[u],     hv, p0);
          p1 = fmaf(w[u + 1], hv, p1);
          p2 = fmaf(w[u + 2], hv, p2);
          p3 = fmaf(w[u + 3], hv, p3);
        }
      }
    }
    *(float4*)&rp[wv][l << 2] = make_float4(p0, p1, p2, p3);
  }
  __syncthreads();

  {
    const int n = m0 + tid;
    float r = 0.f;
    if (n < N_) {
      r = y[(size_t)b * N_ + n];
      if (!first) r -= rp[0][tid] + rp[1][tid] + rp[2][tid] + rp[3][tid];
    }
    rs[tid] = r;
  }
  __syncthreads();

  if (l < 59 && (l << 2) < M_ - m0) {
    float wr[24];
    #pragma unroll
    for (int kk = 0; kk < 6; ++kk) {
      const float4 v = *(const float4*)&rs[(l << 2) + (kk << 2)];
      wr[4*kk+0] = v.x; wr[4*kk+1] = v.y;
      wr[4*kk+2] = v.z; wr[4*kk+3] = v.w;
    }
    #pragma unroll 4
    for (int cl = 0; cl < 16; ++cl) {
      const int cg = __builtin_amdgcn_readfirstlane((wv << 4) + cl);
      const size_t row = ((size_t)b * C_ + cg) * M_ + m0 + (l << 2);
      float xt0, xt1, xt2, xt3;
      if (!first) {
        const float4 a = *(const float4*)(Xc + row);
        float ox = 0.f, oy = 0.f, oz = 0.f, ow = 0.f;
        if (has_o) {
          const float4 o = *(const float4*)(Xo + row);
          ox = o.x; oy = o.y; oz = o.z; ow = o.w;
        }
        xt0 = fmaf(bm, ox, bp * a.x);
        xt1 = fmaf(bm, oy, bp * a.y);
        xt2 = fmaf(bm, oz, bp * a.z);
        xt3 = fmaf(bm, ow, bp * a.w);
      } else { xt0 = xt1 = xt2 = xt3 = 0.f; }
      const float* hc = Hg + cg * K_;
      float a0 = 0.f, a1 = 0.f, a2 = 0.f, a3 = 0.f;
      #pragma unroll
      for (int u = 0; u < 21; ++u) {
        const float hv = hc[u];
        a0 = fmaf(wr[u],     hv, a0);
        a1 = fmaf(wr[u + 1], hv, a1);
        a2 = fmaf(wr[u + 2], hv, a2);
        a3 = fmaf(wr[u + 3], hv, a3);
      }
      const float o0 = fmaxf(fmaf(a0, 0.1f, xt0) - 0.01f, 0.f);
      const float o1 = fmaxf(fmaf(a1, 0.1f, xt1) - 0.01f, 0.f);
      const float o2 = fmaxf(fmaf(a2, 0.1f, xt2) - 0.01f, 0.f);
      const float o3 = fmaxf(fmaf(a3, 0.1f, xt3) - 0.01f, 0.f);
      *(float4*)(Xw + row) = make_float4(o0, o1, o2, o3);
    }
  }
}

#define TA 1024
#define CC 16

__global__ __launch_bounds__(NTF) void convT_kernel(
    const float* __restrict__ X, const float* __restrict__ y,
    const float* __restrict__ Hg, float* __restrict__ out,
    const int use_y, const float sign)
{
  __shared__ float xs[CC][TA + 20];
  __shared__ float hs[C_][K_];
  const int tid = threadIdx.x;
  const int b = blockIdx.y;
  const int n0 = blockIdx.x * TA;

  for (int f = tid; f < C_ * K_; f += NTF) hs[f / K_][f % K_] = sign * Hg[f];

  float acc[4];
  if (use_y) {
    const float4 v = *(const float4*)(y + (size_t)b * N_ + n0 + tid * 4);
    acc[0] = v.x; acc[1] = v.y; acc[2] = v.z; acc[3] = v.w;
  } else {
    acc[0] = acc[1] = acc[2] = acc[3] = 0.f;
  }
  const bool interior = (n0 >= 20) && (n0 + TA - 1 <= M_ - 1);
  const int QROW = (TA + 20) / 4;
  for (int cb = 0; cb < C_; cb += CC) {
    __syncthreads();
    for (int f = tid; f < CC * QROW; f += NTF) {
      const int c = f / QROW;
      const int i = (f % QROW) * 4;
      const int gx = n0 - 20 + i;
      const float* src = X + ((size_t)(b * C_ + cb + c)) * M_ + gx;
      float4 v;
      if (interior) {
        v = *(const float4*)src;
      } else {
        v.x = (gx >= 0     && gx < M_)     ? src[0] : 0.f;
        v.y = (gx + 1 >= 0 && gx + 1 < M_) ? src[1] : 0.f;
        v.z = (gx + 2 >= 0 && gx + 2 < M_) ? src[2] : 0.f;
        v.w = (gx + 3 >= 0 && gx + 3 < M_) ? src[3] : 0.f;
      }
      *(float4*)&xs[c][i] = v;
    }
    __syncthreads();
    for (int c = 0; c < CC; ++c) {
      float w[24];
      #pragma unroll
      for (int k = 0; k < 6; ++k) {
        const float4 v = *(const float4*)&xs[c][tid * 4 + k * 4];
        w[k*4] = v.x; w[k*4+1] = v.y; w[k*4+2] = v.z; w[k*4+3] = v.w;
      }
      const float* hr = hs[cb + c];
      #pragma unroll
      for (int j = 0; j < K_; ++j) {
        const float h = hr[j];
        acc[0] = fmaf(h, w[20 - j], acc[0]);
        acc[1] = fmaf(h, w[21 - j], acc[1]);
        acc[2] = fmaf(h, w[22 - j], acc[2]);
        acc[3] = fmaf(h, w[23 - j], acc[3]);
      }
    }
  }
  *(float4*)(out + (size_t)b * N_ + n0 + tid * 4) =
      make_float4(acc[0], acc[1], acc[2], acc[3]);
}

extern "C" void kernel_launch(void* const* d_in, const int* in_sizes, int n_in,
                              void* d_out, int out_size, void* d_ws, size_t ws_size,
                              hipStream_t stream)
{
  const float* y = (const float*)d_in[0];   // [B,1,N] fp32
  const float* H = (const float*)d_in[1];   // [C,1,K] fp32
  float* out  = (float*)d_out;
  float* outy = out;                         // [B,N] y_hat region
  float* outx = out + (size_t)B_ * N_;       // [B,C,M] x region

  const size_t SZ = (size_t)B_ * C_ * M_;    // floats per x buffer
  const size_t UP = (size_t)B_ * NBLK * UPW; // floats per u buffer

  // FISTA momentum: betas[t] = (s_t - 1)/s_{t+1}, s_0 = 1 (betas[0] = 0)
  float betas[T_];
  double s = 1.0;
  for (int t = 0; t < T_; ++t) {
    const double sn = (1.0 + sqrt(1.0 + 4.0 * s * s)) * 0.5;
    betas[t] = (float)((s - 1.0) / sn);
    s = sn;
  }

  if (ws_size >= (2 * SZ + 3 * UP) * sizeof(float)) {
    // -------- u-recursion path, 2-buffer x rotation (L3-resident) --------
    // x_t lives in buf[t%2]; x_{t+1} overwrites x_{t-1} (legal: own-position
    // read->write per thread). buf0 = outx so x_30 lands in d_out at t=29.
    float* XB[2] = { outx, (float*)d_ws };
    float* U[3]  = { (float*)d_ws + 2 * SZ,
                     (float*)d_ws + 2 * SZ + UP,
                     (float*)d_ws + 2 * SZ + 2 * UP };
    const dim3 gF(NBLK, B_);   // 70 x 32
    const dim3 blkF(NT);       // 512 threads, 8 waves
    for (int t = 0; t < T_; ++t) {
      const float beta = (t >= 1) ? betas[t - 1] : 0.f;
      const float* Xc = XB[t & 1];                       // x_t
      const float* Xo = (beta != 0.f) ? XB[(t + 1) & 1] : Xc;  // x_{t-1}
      float*       Xw = XB[(t + 1) & 1];                 // x_{t+1} over x_{t-1}
      const float* Ut = U[(t + 2) % 3];
      const float* Uo = (beta != 0.f) ? U[(t + 1) % 3] : U[(t + 2) % 3];
      float*       Uw = U[t % 3];
      fused_step4_kernel<<<gF, blkF, 0, stream>>>(
          Xc, Xo, Xw, Ut, Uo, Uw, y, H, 1.f + beta, -beta, t == 0);
    }
    const dim3 gY(N_ / 256, B_);   // 64 x 32
    yhat_combine_kernel<<<gY, dim3(256), 0, stream>>>(U[(T_ - 1) % 3], outy);
  } else {
    // -------- round-5 proven fallback (3-buffer rotation) --------
    float* P[3] = { (float*)d_ws, (float*)d_ws + SZ, outx };
    const dim3 gF((M_ + TILE - 1) / TILE, B_);
    for (int t = 0; t < T_; ++t) {
      const float beta = (t >= 1) ? betas[t - 1] : 0.f;
      const float* Xc = P[(t + 2) % 3];
      const float* Xo = (beta != 0.f) ? P[(t + 1) % 3] : P[(t + 2) % 3];
      float*       Xw = P[t % 3];
      fused_step_r5_kernel<<<gF, dim3(NTF), 0, stream>>>(Xc, Xo, Xw, y, H,
                                                   1.f + beta, -beta, t == 0);
    }
    const dim3 gA(N_ / TA, B_);
    convT_kernel<<<gA, dim3(NTF), 0, stream>>>(outx, y, H, outy, 0, 1.f);
  }
}

// Round 16
// 3304.637 us; speedup vs baseline: 1.0420x; 1.0420x over previous
//
#include <hip/hip_runtime.h>
#include <math.h>

// Problem constants (from reference)
#define B_ 32
#define N_ 16384
#define K_ 21
#define C_ 64
#define M_ (N_ - K_ + 1)   // 16364
#define T_ 30
// L = 10.0, LAM = 0.1  ->  1/L = 0.1, LAM/L = 0.01

#define TILE 236    // x outputs per block
#define NBLK 70     // blocks per batch in m  (70*236 >= M_)
#define UPW  256    // u-partial slots per block (res width)
#define NT   256    // 4 waves; wave wv handles 16 channels

// ---- one chunk-pair loop accumulating into a dedicated p-bank ----
// (two banks halve the cross-channel dependent-FMA chain: 336 -> 168)
#define CHUNK_PAIR(K0, q0, q1, q2, q3)                                      \
  for (int k = (K0); k < (K0) + 2; ++k) {                                   \
    _Pragma("unroll")                                                       \
    for (int j = 0; j < 4; ++j) {                                           \
      const int cg =                                                        \
          __builtin_amdgcn_readfirstlane((k << 4) + (wv << 2) + j);         \
      const float* hc = Hg + cg * K_;   /* uniform -> s_loads */            \
      float g0 = 0.f, g1 = 0.f, g2 = 0.f, g3 = 0.f;                         \
      _Pragma("unroll")                                                     \
      for (int u = 0; u < 21; ++u) {                                        \
        const float hv = hc[u];                                             \
        g0 = fmaf(wr[u],     hv, g0);                                       \
        g1 = fmaf(wr[u + 1], hv, g1);                                       \
        g2 = fmaf(wr[u + 2], hv, g2);                                       \
        g3 = fmaf(wr[u + 3], hv, g3);                                       \
      }                                                                     \
      float xt0 = 0.f, xt1 = 0.f, xt2 = 0.f, xt3 = 0.f;                     \
      if (!first) {                                                         \
        const float4 a = *(const float4*)(Xc + (bC + cg) * M_ + coff);      \
        float ox = 0.f, oy = 0.f, oz = 0.f, ow = 0.f;                       \
        if (has_o) {                                                        \
          const float4 o = *(const float4*)(Xo + (bC + cg) * M_ + coff);    \
          ox = o.x; oy = o.y; oz = o.z; ow = o.w;                           \
        }                                                                   \
        xt0 = fmaf(bm, ox, bp * a.x);                                       \
        xt1 = fmaf(bm, oy, bp * a.y);                                       \
        xt2 = fmaf(bm, oz, bp * a.z);                                       \
        xt3 = fmaf(bm, ow, bp * a.w);                                       \
      }                                                                     \
      float o0 = fmaxf(fmaf(g0, 0.1f, xt0) - 0.01f, 0.f);                   \
      float o1 = fmaxf(fmaf(g1, 0.1f, xt1) - 0.01f, 0.f);                   \
      float o2 = fmaxf(fmaf(g2, 0.1f, xt2) - 0.01f, 0.f);                   \
      float o3 = fmaxf(fmaf(g3, 0.1f, xt3) - 0.01f, 0.f);                   \
      if (!act) { o0 = 0.f; o1 = 0.f; o2 = 0.f; o3 = 0.f; }                 \
      if (act)                                                              \
        *(float4*)(Xw + (bC + cg) * M_ + mown) =                            \
            make_float4(o0, o1, o2, o3);                                    \
      float w[24];                                                          \
      w[20] = o0; w[21] = o1; w[22] = o2; w[23] = o3;                       \
      _Pragma("unroll")                                                     \
      for (int d = 0; d < 5; ++d) {                                         \
        const int src = l - 5 + d;                                          \
        w[4*d+0] = __shfl(o0, src);                                         \
        w[4*d+1] = __shfl(o1, src);                                         \
        w[4*d+2] = __shfl(o2, src);                                         \
        w[4*d+3] = __shfl(o3, src);                                         \
      }                                                                     \
      _Pragma("unroll")                                                     \
      for (int u = 0; u < 21; ++u) {                                        \
        const float hv = hc[20 - u];                                        \
        q0 = fmaf(w[u],     hv, q0);                                        \
        q1 = fmaf(w[u + 1], hv, q1);                                        \
        q2 = fmaf(w[u + 2], hv, q2);                                        \
        q3 = fmaf(w[u + 3], hv, q3);                                        \
      }                                                                     \
    }                                                                       \
  }

// ---------------- fused step (u-recursion, shuffle-based convT) -----------
// u_t = convT(x_t) kept as per-block partials up[B][NBLK][UPW] (<=2 blocks
// overlap per position -> exact deterministic sum at read time, no atomics).
// Per block (b, x): res tile from y/u; conv(res)+shrink with the residual
// window hoisted in registers; the convT window of the NEW x tile is built
// from each lane's own 4 outputs + 5x4 __shfl from lanes l-5..l-1.
// Left-pad zeros come FREE from shuffle wrap: src<0 wraps to lanes 59..63
// (ds_bpermute mod-64 addressing), whose o values are forced to 0 by the
// act predicate (act => l<59). Split p-accumulator banks (pa: ch 0-31,
// pb: ch 32-63) halve the cross-channel dependent-FMA chain.
// NOTE: NO __launch_bounds__ min-waves hint — round 13 showed it inflates
// FETCH/WRITE ~2-3x (L3 locality destroyed) at same VGPR.
// KEY INVARIANT: x is read/written ONLY at own positions -> x_{t+1} may
// overwrite x_{t-1} in-place (2-buffer rotation, L3-resident working set).
__global__ __launch_bounds__(NT) void fused_step4_kernel(
    const float* __restrict__ Xc, const float* __restrict__ Xo,
    float* __restrict__ Xw,
    const float* __restrict__ Ut, const float* __restrict__ Uo,
    float* __restrict__ Uw,
    const float* __restrict__ y, const float* __restrict__ Hg,
    const float bp, const float bm, const int first)
{
  __shared__ float rs[280];        // residual row (+24 zero tail)
  __shared__ float rp[4][256];     // per-wave convT partials

  const int tid = threadIdx.x;
  const int wv  = tid >> 6;
  const int l   = tid & 63;
  const int b   = blockIdx.y;
  const int x   = blockIdx.x;
  const int m0  = x * TILE;
  const bool has_o = (bm != 0.f);

  if (tid < 24) rs[256 + tid] = 0.f;

  // ---- residual: res = y - bp*u_t - bm*u_{t-1} (per-block u partials) ----
  {
    const int n = m0 + tid;
    float r = 0.f;
    if (n < N_) {
      r = y[(size_t)b * N_ + n];
      if (!first) {
        const float* Ub = Ut + (size_t)b * NBLK * UPW;
        float ut;
        if (tid >= 236) {
          ut = Ub[(x + 1) * UPW + tid - 236] + Ub[x * UPW + tid];
        } else {
          ut = Ub[x * UPW + tid];
          if (tid < 20 && x > 0) ut += Ub[(x - 1) * UPW + 236 + tid];
        }
        r -= bp * ut;
        if (has_o) {
          const float* Vb = Uo + (size_t)b * NBLK * UPW;
          float uo;
          if (tid >= 236) {
            uo = Vb[(x + 1) * UPW + tid - 236] + Vb[x * UPW + tid];
          } else {
            uo = Vb[x * UPW + tid];
            if (tid < 20 && x > 0) uo += Vb[(x - 1) * UPW + 236 + tid];
          }
          r -= bm * uo;
        }
      }
    }
    rs[tid] = r;
  }
  __syncthreads();

  // hoisted loop-invariant residual window (VGPR-resident all kernel)
  float wr[24];
  #pragma unroll
  for (int kk = 0; kk < 6; ++kk) {
    const float4 v = *(const float4*)&rs[(l << 2) + (kk << 2)];
    wr[4*kk+0] = v.x; wr[4*kk+1] = v.y;
    wr[4*kk+2] = v.z; wr[4*kk+3] = v.w;
  }

  const int  mown = m0 + (l << 2);
  const int  coff = (mown <= M_ - 4) ? mown : (M_ - 4);  // branchless loads
  const bool act  = (l < 59) && ((l << 2) < M_ - m0);
  const size_t bC = (size_t)b * C_;

  float pa0 = 0.f, pa1 = 0.f, pa2 = 0.f, pa3 = 0.f;   // bank A: ch 0-31
  float pb0 = 0.f, pb1 = 0.f, pb2 = 0.f, pb3 = 0.f;   // bank B: ch 32-63

  CHUNK_PAIR(0, pa0, pa1, pa2, pa3)
  CHUNK_PAIR(2, pb0, pb1, pb2, pb3)

  rp[wv][(l<<2)+0] = pa0 + pb0;
  rp[wv][(l<<2)+1] = pa1 + pb1;
  rp[wv][(l<<2)+2] = pa2 + pb2;
  rp[wv][(l<<2)+3] = pa3 + pb3;
  __syncthreads();

  Uw[((size_t)b * NBLK + x) * UPW + tid] =
      rp[0][tid] + rp[1][tid] + rp[2][tid] + rp[3][tid];
}

// y_hat[n] = u_30(n) from per-block partials (<=2 contributions)
__global__ __launch_bounds__(NT) void yhat_combine_kernel(
    const float* __restrict__ Uw, float* __restrict__ outy)
{
  const int tid = threadIdx.x;
  const int n = blockIdx.x * 256 + tid;
  const int b = blockIdx.y;
  const int x = n / 236;
  const int i = n - x * 236;
  const float* Ub = Uw + (size_t)b * NBLK * UPW;
  float v = Ub[x * UPW + i];
  if (i < 20 && x > 0) v += Ub[(x - 1) * UPW + 236 + i];
  outy[(size_t)b * N_ + n] = v;
}

// ================= round-5 proven fallback path =================
#define XWID 276
#define Q4PC 69
#define NQ4  (16 * Q4PC)

__global__ __launch_bounds__(NT, 4) void fused_step_r5_kernel(
    const float* __restrict__ Xc, const float* __restrict__ Xo,
    float* __restrict__ Xw, const float* __restrict__ y,
    const float* __restrict__ Hg, const float bp, const float bm,
    const int first)
{
  __shared__ float xs[16][XWID];
  __shared__ float rp[4][256];
  __shared__ float rs[256];

  const int tid = threadIdx.x;
  const int wv  = tid >> 6;
  const int l   = tid & 63;
  const int b   = blockIdx.y;
  const int m0  = blockIdx.x * TILE;
  const int g0  = m0 - 20;
  const bool has_o = (bm != 0.f);

  if (!first) {
    float p0 = 0.f, p1 = 0.f, p2 = 0.f, p3 = 0.f;
    for (int k = 0; k < 4; ++k) {
      const int ch0 = k << 4;
      const float* pcb = Xc + ((size_t)b * C_ + ch0) * M_;
      const float* pob = Xo + ((size_t)b * C_ + ch0) * M_;
      __syncthreads();
      for (int f = tid; f < NQ4; f += NT) {
        const int c  = f / Q4PC;
        const int i4 = f - c * Q4PC;
        const int g  = g0 + (i4 << 2);
        const float* pa = pcb + (size_t)c * M_ + g;
        const float* pb = pob + (size_t)c * M_ + g;
        float ax, ay, az, aw, ox, oy, oz, ow;
        if (g >= 0 && g + 3 < M_) {
          const float4 a = *(const float4*)pa;
          ax = a.x; ay = a.y; az = a.z; aw = a.w;
          if (has_o) {
            const float4 o = *(const float4*)pb;
            ox = o.x; oy = o.y; oz = o.z; ow = o.w;
          } else { ox = oy = oz = ow = 0.f; }
        } else {
          ax = ay = az = aw = ox = oy = oz = ow = 0.f;
          if ((unsigned)(g+0) < (unsigned)M_) { ax = pa[0]; if (has_o) ox = pb[0]; }
          if ((unsigned)(g+1) < (unsigned)M_) { ay = pa[1]; if (has_o) oy = pb[1]; }
          if ((unsigned)(g+2) < (unsigned)M_) { az = pa[2]; if (has_o) oz = pb[2]; }
          if ((unsigned)(g+3) < (unsigned)M_) { aw = pa[3]; if (has_o) ow = pb[3]; }
        }
        float4 w4;
        w4.x = fmaf(bm, ox, bp * ax);
        w4.y = fmaf(bm, oy, bp * ay);
        w4.z = fmaf(bm, oz, bp * az);
        w4.w = fmaf(bm, ow, bp * aw);
        *(float4*)&xs[c][i4 << 2] = w4;
      }
      __syncthreads();
      #pragma unroll
      for (int j = 0; j < 4; ++j) {
        const int cloc = (wv << 2) + j;
        const int cg = __builtin_amdgcn_readfirstlane(ch0 + cloc);
        const float* hc = Hg + cg * K_;
        float w[24];
        #pragma unroll
        for (int kk = 0; kk < 6; ++kk) {
          const float4 v = *(const float4*)&xs[cloc][(l << 2) + (kk << 2)];
          w[4*kk+0] = v.x; w[4*kk+1] = v.y;
          w[4*kk+2] = v.z; w[4*kk+3] = v.w;
        }
        #pragma unroll
        for (int u = 0; u < 21; ++u) {
          const float hv = hc[20 - u];
          p0 = fmaf(w[u],     hv, p0);
          p1 = fmaf(w[u + 1], hv, p1);
          p2 = fmaf(w[u + 2], hv, p2);
          p3 = fmaf(w[u + 3], hv, p3);
        }
      }
    }
    *(float4*)&rp[wv][l << 2] = make_float4(p0, p1, p2, p3);
  }
  __syncthreads();

  {
    const int n = m0 + tid;
    float r = 0.f;
    if (n < N_) {
      r = y[(size_t)b * N_ + n];
      if (!first) r -= rp[0][tid] + rp[1][tid] + rp[2][tid] + rp[3][tid];
    }
    rs[tid] = r;
  }
  __syncthreads();

  if (l < 59 && (l << 2) < M_ - m0) {
    float wr[24];
    #pragma unroll
    for (int kk = 0; kk < 6; ++kk) {
      const float4 v = *(const float4*)&rs[(l << 2) + (kk << 2)];
      wr[4*kk+0] = v.x; wr[4*kk+1] = v.y;
      wr[4*kk+2] = v.z; wr[4*kk+3] = v.w;
    }
    #pragma unroll 4
    for (int cl = 0; cl < 16; ++cl) {
      const int cg = __builtin_amdgcn_readfirstlane((wv << 4) + cl);
      const size_t row = ((size_t)b * C_ + cg) * M_ + m0 + (l << 2);
      float xt0, xt1, xt2, xt3;
      if (!first) {
        const float4 a = *(const float4*)(Xc + row);
        float ox = 0.f, oy = 0.f, oz = 0.f, ow = 0.f;
        if (has_o) {
          const float4 o = *(const float4*)(Xo + row);
          ox = o.x; oy = o.y; oz = o.z; ow = o.w;
        }
        xt0 = fmaf(bm, ox, bp * a.x);
        xt1 = fmaf(bm, oy, bp * a.y);
        xt2 = fmaf(bm, oz, bp * a.z);
        xt3 = fmaf(bm, ow, bp * a.w);
      } else { xt0 = xt1 = xt2 = xt3 = 0.f; }
      const float* hc = Hg + cg * K_;
      float a0 = 0.f, a1 = 0.f, a2 = 0.f, a3 = 0.f;
      #pragma unroll
      for (int u = 0; u < 21; ++u) {
        const float hv = hc[u];
        a0 = fmaf(wr[u],     hv, a0);
        a1 = fmaf(wr[u + 1], hv, a1);
        a2 = fmaf(wr[u + 2], hv, a2);
        a3 = fmaf(wr[u + 3], hv, a3);
      }
      const float o0 = fmaxf(fmaf(a0, 0.1f, xt0) - 0.01f, 0.f);
      const float o1 = fmaxf(fmaf(a1, 0.1f, xt1) - 0.01f, 0.f);
      const float o2 = fmaxf(fmaf(a2, 0.1f, xt2) - 0.01f, 0.f);
      const float o3 = fmaxf(fmaf(a3, 0.1f, xt3) - 0.01f, 0.f);
      *(float4*)(Xw + row) = make_float4(o0, o1, o2, o3);
    }
  }
}

#define TA 1024
#define CC 16

__global__ __launch_bounds__(NT) void convT_kernel(
    const float* __restrict__ X, const float* __restrict__ y,
    const float* __restrict__ Hg, float* __restrict__ out,
    const int use_y, const float sign)
{
  __shared__ float xs[CC][TA + 20];
  __shared__ float hs[C_][K_];
  const int tid = threadIdx.x;
  const int b = blockIdx.y;
  const int n0 = blockIdx.x * TA;

  for (int f = tid; f < C_ * K_; f += NT) hs[f / K_][f % K_] = sign * Hg[f];

  float acc[4];
  if (use_y) {
    const float4 v = *(const float4*)(y + (size_t)b * N_ + n0 + tid * 4);
    acc[0] = v.x; acc[1] = v.y; acc[2] = v.z; acc[3] = v.w;
  } else {
    acc[0] = acc[1] = acc[2] = acc[3] = 0.f;
  }
  const bool interior = (n0 >= 20) && (n0 + TA - 1 <= M_ - 1);
  const int QROW = (TA + 20) / 4;
  for (int cb = 0; cb < C_; cb += CC) {
    __syncthreads();
    for (int f = tid; f < CC * QROW; f += NT) {
      const int c = f / QROW;
      const int i = (f % QROW) * 4;
      const int gx = n0 - 20 + i;
      const float* src = X + ((size_t)(b * C_ + cb + c)) * M_ + gx;
      float4 v;
      if (interior) {
        v = *(const float4*)src;
      } else {
        v.x = (gx >= 0     && gx < M_)     ? src[0] : 0.f;
        v.y = (gx + 1 >= 0 && gx + 1 < M_) ? src[1] : 0.f;
        v.z = (gx + 2 >= 0 && gx + 2 < M_) ? src[2] : 0.f;
        v.w = (gx + 3 >= 0 && gx + 3 < M_) ? src[3] : 0.f;
      }
      *(float4*)&xs[c][i] = v;
    }
    __syncthreads();
    for (int c = 0; c < CC; ++c) {
      float w[24];
      #pragma unroll
      for (int k = 0; k < 6; ++k) {
        const float4 v = *(const float4*)&xs[c][tid * 4 + k * 4];
        w[k*4] = v.x; w[k*4+1] = v.y; w[k*4+2] = v.z; w[k*4+3] = v.w;
      }
      const float* hr = hs[cb + c];
      #pragma unroll
      for (int j = 0; j < K_; ++j) {
        const float h = hr[j];
        acc[0] = fmaf(h, w[20 - j], acc[0]);
        acc[1] = fmaf(h, w[21 - j], acc[1]);
        acc[2] = fmaf(h, w[22 - j], acc[2]);
        acc[3] = fmaf(h, w[23 - j], acc[3]);
      }
    }
  }
  *(float4*)(out + (size_t)b * N_ + n0 + tid * 4) =
      make_float4(acc[0], acc[1], acc[2], acc[3]);
}

extern "C" void kernel_launch(void* const* d_in, const int* in_sizes, int n_in,
                              void* d_out, int out_size, void* d_ws, size_t ws_size,
                              hipStream_t stream)
{
  const float* y = (const float*)d_in[0];   // [B,1,N] fp32
  const float* H = (const float*)d_in[1];   // [C,1,K] fp32
  float* out  = (float*)d_out;
  float* outy = out;                         // [B,N] y_hat region
  float* outx = out + (size_t)B_ * N_;       // [B,C,M] x region

  const size_t SZ = (size_t)B_ * C_ * M_;    // floats per x buffer
  const size_t UP = (size_t)B_ * NBLK * UPW; // floats per u buffer

  // FISTA momentum: betas[t] = (s_t - 1)/s_{t+1}, s_0 = 1 (betas[0] = 0)
  float betas[T_];
  double s = 1.0;
  for (int t = 0; t < T_; ++t) {
    const double sn = (1.0 + sqrt(1.0 + 4.0 * s * s)) * 0.5;
    betas[t] = (float)((s - 1.0) / sn);
    s = sn;
  }

  const dim3 blk(NT);

  if (ws_size >= (2 * SZ + 3 * UP) * sizeof(float)) {
    // -------- u-recursion path, 2-buffer x rotation (L3-resident) --------
    // x_t lives in buf[t%2]; x_{t+1} overwrites x_{t-1} (legal: own-position
    // read->write per thread). buf0 = outx so x_30 lands in d_out at t=29.
    float* XB[2] = { outx, (float*)d_ws };
    float* U[3]  = { (float*)d_ws + 2 * SZ,
                     (float*)d_ws + 2 * SZ + UP,
                     (float*)d_ws + 2 * SZ + 2 * UP };
    const dim3 gF(NBLK, B_);   // 70 x 32
    for (int t = 0; t < T_; ++t) {
      const float beta = (t >= 1) ? betas[t - 1] : 0.f;
      const float* Xc = XB[t & 1];                       // x_t
      const float* Xo = (beta != 0.f) ? XB[(t + 1) & 1] : Xc;  // x_{t-1}
      float*       Xw = XB[(t + 1) & 1];                 // x_{t+1} over x_{t-1}
      const float* Ut = U[(t + 2) % 3];
      const float* Uo = (beta != 0.f) ? U[(t + 1) % 3] : U[(t + 2) % 3];
      float*       Uw = U[t % 3];
      fused_step4_kernel<<<gF, blk, 0, stream>>>(
          Xc, Xo, Xw, Ut, Uo, Uw, y, H, 1.f + beta, -beta, t == 0);
    }
    const dim3 gY(N_ / 256, B_);   // 64 x 32
    yhat_combine_kernel<<<gY, blk, 0, stream>>>(U[(T_ - 1) % 3], outy);
  } else {
    // -------- round-5 proven fallback (3-buffer rotation) --------
    float* P[3] = { (float*)d_ws, (float*)d_ws + SZ, outx };
    const dim3 gF((M_ + TILE - 1) / TILE, B_);
    for (int t = 0; t < T_; ++t) {
      const float beta = (t >= 1) ? betas[t - 1] : 0.f;
      const float* Xc = P[(t + 2) % 3];
      const float* Xo = (beta != 0.f) ? P[(t + 1) % 3] : P[(t + 2) % 3];
      float*       Xw = P[t % 3];
      fused_step_r5_kernel<<<gF, blk, 0, stream>>>(Xc, Xo, Xw, y, H,
                                                   1.f + beta, -beta, t == 0);
    }
    const dim3 gA(N_ / TA, B_);
    convT_kernel<<<gA, blk, 0, stream>>>(outx, y, H, outy, 0, 1.f);
  }
}

// Round 17
// 2660.951 us; speedup vs baseline: 1.2941x; 1.2419x over previous
//
#include <hip/hip_runtime.h>
#include <hip/hip_cooperative_groups.h>
#include <math.h>

namespace cg = cooperative_groups;

// Problem constants (from reference)
#define B_ 32
#define N_ 16384
#define K_ 21
#define C_ 64
#define M_ (N_ - K_ + 1)   // 16364
#define T_ 30
// L = 10.0, LAM = 0.1  ->  1/L = 0.1, LAM/L = 0.01

#define TILE 236    // x outputs per block
#define NBLK 70     // tiles per batch in m  (70*236 >= M_)
#define UPW  256    // u-partial slots per tile (res width)
#define NT   256    // 4 waves; wave wv handles 16 channels

// ---------------- shared tile body (round-14, proven) ----------------
// u_t = convT(x_t) kept as per-tile partials up[B][NBLK][UPW] (<=2 tiles
// overlap per position -> exact deterministic sum at read time, no atomics).
// res tile from y/u; conv(res)+shrink with the residual window hoisted in
// registers; convT window of the NEW x tile from own 4 outputs + 5x4 __shfl
// from lanes l-5..l-1 (wrap lands on zeroed lanes 59..63 -> free left pad).
// KEY INVARIANT: x read/written ONLY at own positions -> x_{t+1} may
// overwrite x_{t-1} in-place (2-buffer rotation, L3-resident working set).
__device__ __forceinline__ void step_tile(
    const float* __restrict__ Xc, const float* __restrict__ Xo,
    float* __restrict__ Xw,
    const float* __restrict__ Ut, const float* __restrict__ Uo,
    float* __restrict__ Uw,
    const float* __restrict__ y, const float* __restrict__ Hg,
    const float bp, const float bm, const int first,
    const int b, const int x,
    float* __restrict__ rs, float* __restrict__ rpf)
{
  const int tid = threadIdx.x;
  const int wv  = tid >> 6;
  const int l   = tid & 63;
  const int m0  = x * TILE;
  const bool has_o = (bm != 0.f);

  if (tid < 24) rs[256 + tid] = 0.f;

  // residual: res = y - bp*u_t - bm*u_{t-1}
  {
    const int n = m0 + tid;
    float r = 0.f;
    if (n < N_) {
      r = y[(size_t)b * N_ + n];
      if (!first) {
        const float* Ub = Ut + (size_t)b * NBLK * UPW;
        float ut;
        if (tid >= 236) {
          ut = Ub[(x + 1) * UPW + tid - 236] + Ub[x * UPW + tid];
        } else {
          ut = Ub[x * UPW + tid];
          if (tid < 20 && x > 0) ut += Ub[(x - 1) * UPW + 236 + tid];
        }
        r -= bp * ut;
        if (has_o) {
          const float* Vb = Uo + (size_t)b * NBLK * UPW;
          float uo;
          if (tid >= 236) {
            uo = Vb[(x + 1) * UPW + tid - 236] + Vb[x * UPW + tid];
          } else {
            uo = Vb[x * UPW + tid];
            if (tid < 20 && x > 0) uo += Vb[(x - 1) * UPW + 236 + tid];
          }
          r -= bm * uo;
        }
      }
    }
    rs[tid] = r;
  }
  __syncthreads();

  // hoisted loop-invariant residual window
  float wr[24];
  #pragma unroll
  for (int kk = 0; kk < 6; ++kk) {
    const float4 v = *(const float4*)&rs[(l << 2) + (kk << 2)];
    wr[4*kk+0] = v.x; wr[4*kk+1] = v.y;
    wr[4*kk+2] = v.z; wr[4*kk+3] = v.w;
  }

  const int  mown = m0 + (l << 2);
  const int  coff = (mown <= M_ - 4) ? mown : (M_ - 4);
  const bool act  = (l < 59) && ((l << 2) < M_ - m0);
  const size_t bC = (size_t)b * C_;

  float p0 = 0.f, p1 = 0.f, p2 = 0.f, p3 = 0.f;

  for (int k = 0; k < 4; ++k) {
    #pragma unroll
    for (int j = 0; j < 4; ++j) {
      const int cg_ = __builtin_amdgcn_readfirstlane((k << 4) + (wv << 2) + j);
      const float* hc = Hg + cg_ * K_;   // uniform -> s_loads

      float g0 = 0.f, g1 = 0.f, g2 = 0.f, g3 = 0.f;
      #pragma unroll
      for (int u = 0; u < 21; ++u) {
        const float hv = hc[u];
        g0 = fmaf(wr[u],     hv, g0);
        g1 = fmaf(wr[u + 1], hv, g1);
        g2 = fmaf(wr[u + 2], hv, g2);
        g3 = fmaf(wr[u + 3], hv, g3);
      }

      float xt0 = 0.f, xt1 = 0.f, xt2 = 0.f, xt3 = 0.f;
      if (!first) {
        const float4 a = *(const float4*)(Xc + (bC + cg_) * M_ + coff);
        float ox = 0.f, oy = 0.f, oz = 0.f, ow = 0.f;
        if (has_o) {
          const float4 o = *(const float4*)(Xo + (bC + cg_) * M_ + coff);
          ox = o.x; oy = o.y; oz = o.z; ow = o.w;
        }
        xt0 = fmaf(bm, ox, bp * a.x);
        xt1 = fmaf(bm, oy, bp * a.y);
        xt2 = fmaf(bm, oz, bp * a.z);
        xt3 = fmaf(bm, ow, bp * a.w);
      }

      float o0 = fmaxf(fmaf(g0, 0.1f, xt0) - 0.01f, 0.f);
      float o1 = fmaxf(fmaf(g1, 0.1f, xt1) - 0.01f, 0.f);
      float o2 = fmaxf(fmaf(g2, 0.1f, xt2) - 0.01f, 0.f);
      float o3 = fmaxf(fmaf(g3, 0.1f, xt3) - 0.01f, 0.f);
      if (!act) { o0 = 0.f; o1 = 0.f; o2 = 0.f; o3 = 0.f; }
      if (act)
        *(float4*)(Xw + (bC + cg_) * M_ + mown) = make_float4(o0, o1, o2, o3);

      float w[24];
      w[20] = o0; w[21] = o1; w[22] = o2; w[23] = o3;
      #pragma unroll
      for (int d = 0; d < 5; ++d) {
        const int src = l - 5 + d;
        w[4*d+0] = __shfl(o0, src);
        w[4*d+1] = __shfl(o1, src);
        w[4*d+2] = __shfl(o2, src);
        w[4*d+3] = __shfl(o3, src);
      }

      #pragma unroll
      for (int u = 0; u < 21; ++u) {
        const float hv = hc[20 - u];
        p0 = fmaf(w[u],     hv, p0);
        p1 = fmaf(w[u + 1], hv, p1);
        p2 = fmaf(w[u + 2], hv, p2);
        p3 = fmaf(w[u + 3], hv, p3);
      }
    }
  }

  rpf[(wv << 8) + (l << 2) + 0] = p0;
  rpf[(wv << 8) + (l << 2) + 1] = p1;
  rpf[(wv << 8) + (l << 2) + 2] = p2;
  rpf[(wv << 8) + (l << 2) + 3] = p3;
  __syncthreads();

  Uw[((size_t)b * NBLK + x) * UPW + tid] =
      rpf[tid] + rpf[256 + tid] + rpf[512 + tid] + rpf[768 + tid];
}

// ---------------- cooperative persistent kernel (all 30 iters) -----------
struct CoopArgs {
  const float* y; const float* Hg;
  float* x0; float* x1;          // x 2-buffer rotation
  float* u0; float* u1; float* u2;
  float* outy;
  float bp[T_]; float bm[T_];
};

__global__ __launch_bounds__(NT) void fista_coop_kernel(CoopArgs a)
{
  __shared__ float rs[280];
  __shared__ float rp[4 * 256];
  cg::grid_group grid = cg::this_grid();

  float* XB[2] = { a.x0, a.x1 };
  float* U[3]  = { a.u0, a.u1, a.u2 };

  for (int t = 0; t < T_; ++t) {
    const float bp = a.bp[t], bm = a.bm[t];
    const int first = (t == 0);
    const float* Xc = XB[t & 1];
    float*       Xw = XB[(t + 1) & 1];
    const float* Xo = (bm != 0.f) ? XB[(t + 1) & 1] : Xc;
    const float* Ut = U[(t + 2) % 3];
    const float* Uo = (bm != 0.f) ? U[(t + 1) % 3] : U[(t + 2) % 3];
    float*       Uw = U[t % 3];

    for (int tile = blockIdx.x; tile < B_ * NBLK; tile += gridDim.x) {
      const int b = tile / NBLK;
      const int x = tile - b * NBLK;
      step_tile(Xc, Xo, Xw, Ut, Uo, Uw, a.y, a.Hg, bp, bm, first, b, x,
                rs, rp);
    }
    grid.sync();   // Xw/Uw visible (device scope) before next iteration
  }

  // y_hat = u_30 from per-tile partials (<=2 contributions)
  const float* Uf = U[(T_ - 1) % 3];
  for (int tile = blockIdx.x; tile < 64 * B_; tile += gridDim.x) {
    const int b = tile >> 6;
    const int n = ((tile & 63) << 8) + threadIdx.x;
    const int xq = n / 236;
    const int i  = n - xq * 236;
    const float* Ub = Uf + (size_t)b * NBLK * UPW;
    float v = Ub[xq * UPW + i];
    if (i < 20 && xq > 0) v += Ub[(xq - 1) * UPW + 236 + i];
    a.outy[(size_t)b * N_ + n] = v;
  }
}

// ---------------- round-14 multi-dispatch fallback ----------------
__global__ __launch_bounds__(NT) void fused_step4_kernel(
    const float* __restrict__ Xc, const float* __restrict__ Xo,
    float* __restrict__ Xw,
    const float* __restrict__ Ut, const float* __restrict__ Uo,
    float* __restrict__ Uw,
    const float* __restrict__ y, const float* __restrict__ Hg,
    const float bp, const float bm, const int first)
{
  __shared__ float rs[280];
  __shared__ float rp[4 * 256];
  step_tile(Xc, Xo, Xw, Ut, Uo, Uw, y, Hg, bp, bm, first,
            blockIdx.y, blockIdx.x, rs, rp);
}

__global__ __launch_bounds__(NT) void yhat_combine_kernel(
    const float* __restrict__ Uw, float* __restrict__ outy)
{
  const int tid = threadIdx.x;
  const int n = blockIdx.x * 256 + tid;
  const int b = blockIdx.y;
  const int x = n / 236;
  const int i = n - x * 236;
  const float* Ub = Uw + (size_t)b * NBLK * UPW;
  float v = Ub[x * UPW + i];
  if (i < 20 && x > 0) v += Ub[(x - 1) * UPW + 236 + i];
  outy[(size_t)b * N_ + n] = v;
}

// ================= round-5 proven minimal-ws fallback =================
#define XWID 276
#define Q4PC 69
#define NQ4  (16 * Q4PC)

__global__ __launch_bounds__(NT, 4) void fused_step_r5_kernel(
    const float* __restrict__ Xc, const float* __restrict__ Xo,
    float* __restrict__ Xw, const float* __restrict__ y,
    const float* __restrict__ Hg, const float bp, const float bm,
    const int first)
{
  __shared__ float xs[16][XWID];
  __shared__ float rp[4][256];
  __shared__ float rs[256];

  const int tid = threadIdx.x;
  const int wv  = tid >> 6;
  const int l   = tid & 63;
  const int b   = blockIdx.y;
  const int m0  = blockIdx.x * TILE;
  const int g0  = m0 - 20;
  const bool has_o = (bm != 0.f);

  if (!first) {
    float p0 = 0.f, p1 = 0.f, p2 = 0.f, p3 = 0.f;
    for (int k = 0; k < 4; ++k) {
      const int ch0 = k << 4;
      const float* pcb = Xc + ((size_t)b * C_ + ch0) * M_;
      const float* pob = Xo + ((size_t)b * C_ + ch0) * M_;
      __syncthreads();
      for (int f = tid; f < NQ4; f += NT) {
        const int c  = f / Q4PC;
        const int i4 = f - c * Q4PC;
        const int g  = g0 + (i4 << 2);
        const float* pa = pcb + (size_t)c * M_ + g;
        const float* pb = pob + (size_t)c * M_ + g;
        float ax, ay, az, aw, ox, oy, oz, ow;
        if (g >= 0 && g + 3 < M_) {
          const float4 a = *(const float4*)pa;
          ax = a.x; ay = a.y; az = a.z; aw = a.w;
          if (has_o) {
            const float4 o = *(const float4*)pb;
            ox = o.x; oy = o.y; oz = o.z; ow = o.w;
          } else { ox = oy = oz = ow = 0.f; }
        } else {
          ax = ay = az = aw = ox = oy = oz = ow = 0.f;
          if ((unsigned)(g+0) < (unsigned)M_) { ax = pa[0]; if (has_o) ox = pb[0]; }
          if ((unsigned)(g+1) < (unsigned)M_) { ay = pa[1]; if (has_o) oy = pb[1]; }
          if ((unsigned)(g+2) < (unsigned)M_) { az = pa[2]; if (has_o) oz = pb[2]; }
          if ((unsigned)(g+3) < (unsigned)M_) { aw = pa[3]; if (has_o) ow = pb[3]; }
        }
        float4 w4;
        w4.x = fmaf(bm, ox, bp * ax);
        w4.y = fmaf(bm, oy, bp * ay);
        w4.z = fmaf(bm, oz, bp * az);
        w4.w = fmaf(bm, ow, bp * aw);
        *(float4*)&xs[c][i4 << 2] = w4;
      }
      __syncthreads();
      #pragma unroll
      for (int j = 0; j < 4; ++j) {
        const int cloc = (wv << 2) + j;
        const int cg_ = __builtin_amdgcn_readfirstlane(ch0 + cloc);
        const float* hc = Hg + cg_ * K_;
        float w[24];
        #pragma unroll
        for (int kk = 0; kk < 6; ++kk) {
          const float4 v = *(const float4*)&xs[cloc][(l << 2) + (kk << 2)];
          w[4*kk+0] = v.x; w[4*kk+1] = v.y;
          w[4*kk+2] = v.z; w[4*kk+3] = v.w;
        }
        #pragma unroll
        for (int u = 0; u < 21; ++u) {
          const float hv = hc[20 - u];
          p0 = fmaf(w[u],     hv, p0);
          p1 = fmaf(w[u + 1], hv, p1);
          p2 = fmaf(w[u + 2], hv, p2);
          p3 = fmaf(w[u + 3], hv, p3);
        }
      }
    }
    *(float4*)&rp[wv][l << 2] = make_float4(p0, p1, p2, p3);
  }
  __syncthreads();

  {
    const int n = m0 + tid;
    float r = 0.f;
    if (n < N_) {
      r = y[(size_t)b * N_ + n];
      if (!first) r -= rp[0][tid] + rp[1][tid] + rp[2][tid] + rp[3][tid];
    }
    rs[tid] = r;
  }
  __syncthreads();

  if (l < 59 && (l << 2) < M_ - m0) {
    float wr[24];
    #pragma unroll
    for (int kk = 0; kk < 6; ++kk) {
      const float4 v = *(const float4*)&rs[(l << 2) + (kk << 2)];
      wr[4*kk+0] = v.x; wr[4*kk+1] = v.y;
      wr[4*kk+2] = v.z; wr[4*kk+3] = v.w;
    }
    #pragma unroll 4
    for (int cl = 0; cl < 16; ++cl) {
      const int cg_ = __builtin_amdgcn_readfirstlane((wv << 4) + cl);
      const size_t row = ((size_t)b * C_ + cg_) * M_ + m0 + (l << 2);
      float xt0, xt1, xt2, xt3;
      if (!first) {
        const float4 a = *(const float4*)(Xc + row);
        float ox = 0.f, oy = 0.f, oz = 0.f, ow = 0.f;
        if (has_o) {
          const float4 o = *(const float4*)(Xo + row);
          ox = o.x; oy = o.y; oz = o.z; ow = o.w;
        }
        xt0 = fmaf(bm, ox, bp * a.x);
        xt1 = fmaf(bm, oy, bp * a.y);
        xt2 = fmaf(bm, oz, bp * a.z);
        xt3 = fmaf(bm, ow, bp * a.w);
      } else { xt0 = xt1 = xt2 = xt3 = 0.f; }
      const float* hc = Hg + cg_ * K_;
      float a0 = 0.f, a1 = 0.f, a2 = 0.f, a3 = 0.f;
      #pragma unroll
      for (int u = 0; u < 21; ++u) {
        const float hv = hc[u];
        a0 = fmaf(wr[u],     hv, a0);
        a1 = fmaf(wr[u + 1], hv, a1);
        a2 = fmaf(wr[u + 2], hv, a2);
        a3 = fmaf(wr[u + 3], hv, a3);
      }
      const float o0 = fmaxf(fmaf(a0, 0.1f, xt0) - 0.01f, 0.f);
      const float o1 = fmaxf(fmaf(a1, 0.1f, xt1) - 0.01f, 0.f);
      const float o2 = fmaxf(fmaf(a2, 0.1f, xt2) - 0.01f, 0.f);
      const float o3 = fmaxf(fmaf(a3, 0.1f, xt3) - 0.01f, 0.f);
      *(float4*)(Xw + row) = make_float4(o0, o1, o2, o3);
    }
  }
}

#define TA 1024
#define CC 16

__global__ __launch_bounds__(NT) void convT_kernel(
    const float* __restrict__ X, const float* __restrict__ y,
    const float* __restrict__ Hg, float* __restrict__ out,
    const int use_y, const float sign)
{
  __shared__ float xs[CC][TA + 20];
  __shared__ float hs[C_][K_];
  const int tid = threadIdx.x;
  const int b = blockIdx.y;
  const int n0 = blockIdx.x * TA;

  for (int f = tid; f < C_ * K_; f += NT) hs[f / K_][f % K_] = sign * Hg[f];

  float acc[4];
  if (use_y) {
    const float4 v = *(const float4*)(y + (size_t)b * N_ + n0 + tid * 4);
    acc[0] = v.x; acc[1] = v.y; acc[2] = v.z; acc[3] = v.w;
  } else {
    acc[0] = acc[1] = acc[2] = acc[3] = 0.f;
  }
  const bool interior = (n0 >= 20) && (n0 + TA - 1 <= M_ - 1);
  const int QROW = (TA + 20) / 4;
  for (int cb = 0; cb < C_; cb += CC) {
    __syncthreads();
    for (int f = tid; f < CC * QROW; f += NT) {
      const int c = f / QROW;
      const int i = (f % QROW) * 4;
      const int gx = n0 - 20 + i;
      const float* src = X + ((size_t)(b * C_ + cb + c)) * M_ + gx;
      float4 v;
      if (interior) {
        v = *(const float4*)src;
      } else {
        v.x = (gx >= 0     && gx < M_)     ? src[0] : 0.f;
        v.y = (gx + 1 >= 0 && gx + 1 < M_) ? src[1] : 0.f;
        v.z = (gx + 2 >= 0 && gx + 2 < M_) ? src[2] : 0.f;
        v.w = (gx + 3 >= 0 && gx + 3 < M_) ? src[3] : 0.f;
      }
      *(float4*)&xs[c][i] = v;
    }
    __syncthreads();
    for (int c = 0; c < CC; ++c) {
      float w[24];
      #pragma unroll
      for (int k = 0; k < 6; ++k) {
        const float4 v = *(const float4*)&xs[c][tid * 4 + k * 4];
        w[k*4] = v.x; w[k*4+1] = v.y; w[k*4+2] = v.z; w[k*4+3] = v.w;
      }
      const float* hr = hs[cb + c];
      #pragma unroll
      for (int j = 0; j < K_; ++j) {
        const float h = hr[j];
        acc[0] = fmaf(h, w[20 - j], acc[0]);
        acc[1] = fmaf(h, w[21 - j], acc[1]);
        acc[2] = fmaf(h, w[22 - j], acc[2]);
        acc[3] = fmaf(h, w[23 - j], acc[3]);
      }
    }
  }
  *(float4*)(out + (size_t)b * N_ + n0 + tid * 4) =
      make_float4(acc[0], acc[1], acc[2], acc[3]);
}

extern "C" void kernel_launch(void* const* d_in, const int* in_sizes, int n_in,
                              void* d_out, int out_size, void* d_ws, size_t ws_size,
                              hipStream_t stream)
{
  const float* y = (const float*)d_in[0];   // [B,1,N] fp32
  const float* H = (const float*)d_in[1];   // [C,1,K] fp32
  float* out  = (float*)d_out;
  float* outy = out;                         // [B,N] y_hat region
  float* outx = out + (size_t)B_ * N_;       // [B,C,M] x region

  const size_t SZ = (size_t)B_ * C_ * M_;    // floats per x buffer
  const size_t UP = (size_t)B_ * NBLK * UPW; // floats per u buffer

  // FISTA momentum: betas[t] = (s_t - 1)/s_{t+1}, s_0 = 1 (betas[0] = 0)
  float betas[T_];
  double s = 1.0;
  for (int t = 0; t < T_; ++t) {
    const double sn = (1.0 + sqrt(1.0 + 4.0 * s * s)) * 0.5;
    betas[t] = (float)((s - 1.0) / sn);
    s = sn;
  }

  const dim3 blk(NT);
  const bool big_ws = ws_size >= (2 * SZ + 3 * UP) * sizeof(float);

  if (big_ws) {
    float* XB[2] = { outx, (float*)d_ws };   // buf0=outx -> x_30 lands in d_out
    float* U[3]  = { (float*)d_ws + 2 * SZ,
                     (float*)d_ws + 2 * SZ + UP,
                     (float*)d_ws + 2 * SZ + 2 * UP };

    // ---- cooperative persistent path (pure host-query gating) ----
    int dev = 0, coopAttr = 0, ncu = 0, maxb = 0;
    bool coop = (hipGetDevice(&dev) == hipSuccess);
    if (coop) coop = (hipDeviceGetAttribute(&coopAttr,
                        hipDeviceAttributeCooperativeLaunch, dev) == hipSuccess)
                     && coopAttr;
    if (coop) coop = (hipDeviceGetAttribute(&ncu,
                        hipDeviceAttributeMultiprocessorCount, dev) == hipSuccess)
                     && ncu > 0;
    if (coop) coop = (hipOccupancyMaxActiveBlocksPerMultiprocessor(
                        &maxb, fista_coop_kernel, NT, 0) == hipSuccess)
                     && maxb >= 1;
    if (coop) {
      int blocks = ncu * (maxb > 8 ? 8 : maxb);   // <= guaranteed co-resident
      if (blocks > B_ * NBLK) blocks = B_ * NBLK;
      CoopArgs a;
      a.y = y; a.Hg = H;
      a.x0 = XB[0]; a.x1 = XB[1];
      a.u0 = U[0]; a.u1 = U[1]; a.u2 = U[2];
      a.outy = outy;
      for (int t = 0; t < T_; ++t) {
        const float beta = (t >= 1) ? betas[t - 1] : 0.f;
        a.bp[t] = 1.f + beta;
        a.bm[t] = -beta;
      }
      void* kp[1] = { (void*)&a };
      if (hipLaunchCooperativeKernel(fista_coop_kernel, dim3(blocks), blk,
                                     kp, 0, stream) == hipSuccess)
        return;
      // fall through to multi-dispatch on failure
    }

    // ---- round-14 multi-dispatch path (proven 2.71 ms) ----
    const dim3 gF(NBLK, B_);   // 70 x 32
    for (int t = 0; t < T_; ++t) {
      const float beta = (t >= 1) ? betas[t - 1] : 0.f;
      const float* Xc = XB[t & 1];
      const float* Xo = (beta != 0.f) ? XB[(t + 1) & 1] : Xc;
      float*       Xw = XB[(t + 1) & 1];
      const float* Ut = U[(t + 2) % 3];
      const float* Uo = (beta != 0.f) ? U[(t + 1) % 3] : U[(t + 2) % 3];
      float*       Uw = U[t % 3];
      fused_step4_kernel<<<gF, blk, 0, stream>>>(
          Xc, Xo, Xw, Ut, Uo, Uw, y, H, 1.f + beta, -beta, t == 0);
    }
    const dim3 gY(N_ / 256, B_);
    yhat_combine_kernel<<<gY, blk, 0, stream>>>(U[(T_ - 1) % 3], outy);
  } else {
    // ---- round-5 proven fallback (3-buffer rotation) ----
    float* P[3] = { (float*)d_ws, (float*)d_ws + SZ, outx };
    const dim3 gF((M_ + TILE - 1) / TILE, B_);
    for (int t = 0; t < T_; ++t) {
      const float beta = (t >= 1) ? betas[t - 1] : 0.f;
      const float* Xc = P[(t + 2) % 3];
      const float* Xo = (beta != 0.f) ? P[(t + 1) % 3] : P[(t + 2) % 3];
      float*       Xw = P[t % 3];
      fused_step_r5_kernel<<<gF, blk, 0, stream>>>(Xc, Xo, Xw, y, H,
                                                   1.f + beta, -beta, t == 0);
    }
    const dim3 gA(N_ / TA, B_);
    convT_kernel<<<gA, blk, 0, stream>>>(outx, y, H, outy, 0, 1.f);
  }
}